// Round 3
// baseline (596.476 us; speedup 1.0000x reference)
//
#include <hip/hip_runtime.h>
#include <hip/hip_bf16.h>

typedef unsigned short u16;
typedef unsigned int u32;
typedef __attribute__((ext_vector_type(8))) short bf16x8;
typedef __attribute__((ext_vector_type(4))) float f32x4;
typedef __attribute__((ext_vector_type(16))) float f32x16;

#define DEVI __device__ __forceinline__

constexpr int S_ = 2048, H_ = 16, D_ = 1024, M_ = 8192;

DEVI u16 f2bf(float f) {
  unsigned int u = __float_as_uint(f);
  u += 0x7fffu + ((u >> 16) & 1u);   // RTNE
  return (u16)(u >> 16);
}
DEVI float bf2f(u16 h) { return __uint_as_float(((unsigned int)h) << 16); }

DEVI f32x4 MFMA16(bf16x8 a, bf16x8 b, f32x4 c) {
  return __builtin_amdgcn_mfma_f32_16x16x32_bf16(a, b, c, 0, 0, 0);
}
DEVI f32x16 MFMA32(bf16x8 a, bf16x8 b, f32x16 c) {
  return __builtin_amdgcn_mfma_f32_32x32x16_bf16(a, b, c, 0, 0, 0);
}

// ---------------------------------------------------------------------------
// GEMM: C[m][n] = sum_k A[m][k] * W[n][k] + bias[n]   (A: M x 1024, W: 1024 x 1024)
// TERMS=3: error-compensated hi/lo split. TERMS=1: plain bf16 path.
// EPI=0: write (v*oscale) as bf16 hi+lo scattered to (B,H,S,DK)   (Q/K proj)
// EPI=1: MFMA operands swapped (acc holds C^T); write bf16 V^T [bh][dk][s]
// EPI=2: A is bf16 row-major; write f32 row-major                 (out proj)
// ---------------------------------------------------------------------------
template<int TERMS, int EPI>
__global__ __launch_bounds__(256)
void gemm_k(const float* __restrict__ Af, const u16* __restrict__ Ab,
            const float* __restrict__ W, const float* __restrict__ bias,
            u16* __restrict__ oB, float* __restrict__ oLoF, float oscale)
{
  constexpr int LDT = 40;                      // 80B row stride
  __shared__ u16 Ah[128 * LDT];
  __shared__ u16 Al[(TERMS == 3) ? 128 * LDT : 8];
  __shared__ u16 Wh[128 * LDT];
  __shared__ u16 Wl[(TERMS == 3) ? 128 * LDT : 8];

  const int tid = threadIdx.x;
  const int lane = tid & 63;
  const int wv = tid >> 6;
  const int wr = wv >> 1, wc = wv & 1;
  const int l15 = lane & 15, l16 = lane >> 4;
  const int m0 = blockIdx.y * 128, n0 = blockIdx.x * 128;

  f32x4 acc[4][4];
  for (int i = 0; i < 4; ++i)
    for (int j = 0; j < 4; ++j) acc[i][j] = f32x4{0.f, 0.f, 0.f, 0.f};

  for (int kt = 0; kt < D_; kt += 32) {
    __syncthreads();
    if constexpr (EPI == 2) {
      const int r = tid >> 2, c = (tid & 3) * 8;
      for (int p = 0; p < 2; ++p) {
        const int row = r + p * 64;
        bf16x8 v = *(const bf16x8*)(Ab + (size_t)(m0 + row) * D_ + kt + c);
        *(bf16x8*)&Ah[row * LDT + c] = v;
      }
    } else {
      const int r = tid >> 3, c = (tid & 7) * 4;
      for (int p = 0; p < 4; ++p) {
        const int row = r + p * 32;
        float4 v = *(const float4*)(Af + (size_t)(m0 + row) * D_ + kt + c);
        u16 h0 = f2bf(v.x), h1 = f2bf(v.y), h2 = f2bf(v.z), h3 = f2bf(v.w);
        *(ushort4*)&Ah[row * LDT + c] = make_ushort4(h0, h1, h2, h3);
        if constexpr (TERMS == 3) {
          *(ushort4*)&Al[row * LDT + c] =
              make_ushort4(f2bf(v.x - bf2f(h0)), f2bf(v.y - bf2f(h1)),
                           f2bf(v.z - bf2f(h2)), f2bf(v.w - bf2f(h3)));
        }
      }
    }
    {
      const int r = tid >> 3, c = (tid & 7) * 4;
      for (int p = 0; p < 4; ++p) {
        const int row = r + p * 32;
        float4 v = *(const float4*)(W + (size_t)(n0 + row) * D_ + kt + c);
        u16 h0 = f2bf(v.x), h1 = f2bf(v.y), h2 = f2bf(v.z), h3 = f2bf(v.w);
        *(ushort4*)&Wh[row * LDT + c] = make_ushort4(h0, h1, h2, h3);
        if constexpr (TERMS == 3) {
          *(ushort4*)&Wl[row * LDT + c] =
              make_ushort4(f2bf(v.x - bf2f(h0)), f2bf(v.y - bf2f(h1)),
                           f2bf(v.z - bf2f(h2)), f2bf(v.w - bf2f(h3)));
        }
      }
    }
    __syncthreads();

    bf16x8 a_hi[4], w_hi[4], a_lo[4], w_lo[4];
    for (int i = 0; i < 4; ++i) {
      const int row = wr * 64 + i * 16 + l15;
      a_hi[i] = *(const bf16x8*)&Ah[row * LDT + l16 * 8];
      if constexpr (TERMS == 3) a_lo[i] = *(const bf16x8*)&Al[row * LDT + l16 * 8];
    }
    for (int j = 0; j < 4; ++j) {
      const int row = wc * 64 + j * 16 + l15;
      w_hi[j] = *(const bf16x8*)&Wh[row * LDT + l16 * 8];
      if constexpr (TERMS == 3) w_lo[j] = *(const bf16x8*)&Wl[row * LDT + l16 * 8];
    }
    for (int i = 0; i < 4; ++i)
      for (int j = 0; j < 4; ++j) {
        if constexpr (EPI == 1) {
          acc[i][j] = MFMA16(w_hi[j], a_hi[i], acc[i][j]);   // C^T
        } else {
          acc[i][j] = MFMA16(a_hi[i], w_hi[j], acc[i][j]);
          if constexpr (TERMS == 3) {
            acc[i][j] = MFMA16(a_hi[i], w_lo[j], acc[i][j]);
            acc[i][j] = MFMA16(a_lo[i], w_hi[j], acc[i][j]);
          }
        }
      }
  }

  if constexpr (EPI == 1) {
    // acc[i][j]: rows = n (l16*4+r), cols = m (l15). Write V^T coalesced in s.
    for (int j = 0; j < 4; ++j)
      for (int i = 0; i < 4; ++i)
        for (int r = 0; r < 4; ++r) {
          const int n = n0 + wc * 64 + j * 16 + l16 * 4 + r;
          const int m = m0 + wr * 64 + i * 16 + l15;
          const float v = (acc[i][j][r] + bias[n]) * oscale;
          const int b = m >> 11, s = m & 2047, h = n >> 6, dk = n & 63;
          oB[((size_t)(b * H_ + h) * 64 + dk) * S_ + s] = f2bf(v);
        }
  } else {
    for (int j = 0; j < 4; ++j) {
      const int n = n0 + wc * 64 + j * 16 + l15;
      const float bj = bias[n];
      for (int i = 0; i < 4; ++i)
        for (int r = 0; r < 4; ++r) {
          const int m = m0 + wr * 64 + i * 16 + l16 * 4 + r;
          const float v = (acc[i][j][r] + bj) * oscale;
          if constexpr (EPI == 2) {
            oLoF[(size_t)m * D_ + n] = v;
          } else {
            const int b = m >> 11, s = m & 2047, h = n >> 6, dk = n & 63;
            const size_t idx = ((size_t)(b * H_ + h) * S_ + s) * 64 + dk;
            const u16 hv = f2bf(v);
            oB[idx] = hv;
            ((u16*)oLoF)[idx] = f2bf(v - bf2f(hv));
          }
        }
    }
  }
}

// ---------------------------------------------------------------------------
__global__ void maskpack_k(const int* __restrict__ pad, u32* __restrict__ mb) {
  const int t = threadIdx.x;                   // 256 words cover 4*2048 ints
  u32 w = 0;
  for (int i = 0; i < 32; ++i) w |= (pad[t * 32 + i] ? 1u : 0u) << i;
  mb[t] = w;
}

// ---------------------------------------------------------------------------
// Fused flash attention, no LDS, 32x32 MFMA, swapped QK^T (S^T = K*Q^T).
// Each wave owns 32 q-rows of one (b,h); K/V read direct from global (L2-fit).
// Per lane: 32 scores for ONE q-row -> in-lane softmax + 1 shfl_xor(32).
// P packed to bf16 in-register via v_cvt_pk_bf16_f32 + v_permlane32_swap.
// permlane32_swap(vdst=LOW-k word, vsrc=HIGH-k word): exchanges
// vdst.lanes[32:63] <-> vsrc.lanes[0:31]  (m214-verified operand order).
// 1/sqrt(64) pre-folded into Q projection. mrun init 0 (shift-invariant).
// ---------------------------------------------------------------------------
__global__ __launch_bounds__(256)
void attn_k(const u16* __restrict__ Qhi, const u16* __restrict__ Qlo,
            const u16* __restrict__ Khi, const u16* __restrict__ Klo,
            const u16* __restrict__ Vt, const u32* __restrict__ mb,
            u16* __restrict__ Xo)
{
  const int tid = threadIdx.x;
  const int lane = tid & 63;
  const int wv = tid >> 6;
  const int l31 = lane & 31;
  const int hi = lane >> 5;
  const int h = blockIdx.y, b = blockIdx.z;
  const int bh = b * H_ + h;
  const int q = blockIdx.x * 128 + wv * 32 + l31;

  const u16* Qh = Qhi + (size_t)bh * S_ * 64;
  const u16* Ql = Qlo + (size_t)bh * S_ * 64;
  const u16* Kh = Khi + (size_t)bh * S_ * 64;
  const u16* Kl = Klo + (size_t)bh * S_ * 64;
  const u16* Vb = Vt + (size_t)bh * 64 * S_;
  const u32* mbb = mb + b * (S_ / 32);

  bf16x8 qh[4], ql[4];
#pragma unroll
  for (int ds = 0; ds < 4; ++ds) {
    qh[ds] = *(const bf16x8*)(Qh + (size_t)q * 64 + ds * 16 + hi * 8);
    ql[ds] = *(const bf16x8*)(Ql + (size_t)q * 64 + ds * 16 + hi * 8);
  }

  f32x16 xacc0, xacc1;
#pragma unroll
  for (int r = 0; r < 16; ++r) { xacc0[r] = 0.f; xacc1[r] = 0.f; }
  float mrun = 0.f, lrun = 0.f;

  for (int k0 = 0; k0 < S_; k0 += 64) {
    // ---- QK^T: S^T[k][q], 2 sub-tiles of 32 k, 3-term hi/lo ----
    f32x16 s0, s1;
#pragma unroll
    for (int r = 0; r < 16; ++r) { s0[r] = 0.f; s1[r] = 0.f; }
#pragma unroll
    for (int st = 0; st < 2; ++st) {
      const u16* kbh = Kh + (size_t)(k0 + st * 32 + l31) * 64 + hi * 8;
      const u16* kbl = Kl + (size_t)(k0 + st * 32 + l31) * 64 + hi * 8;
      f32x16& sS = st ? s1 : s0;
#pragma unroll
      for (int ds = 0; ds < 4; ++ds) {
        bf16x8 kh = *(const bf16x8*)(kbh + ds * 16);
        bf16x8 kl = *(const bf16x8*)(kbl + ds * 16);
        sS = MFMA32(kh, qh[ds], sS);
        sS = MFMA32(kl, qh[ds], sS);
        sS = MFMA32(kh, ql[ds], sS);
      }
    }

    // ---- mask + tile max (scores pre-scaled via Q) ----
    const u32 mw0 = mbb[(k0 >> 5) + 0] >> (hi * 4);
    const u32 mw1 = mbb[(k0 >> 5) + 1] >> (hi * 4);
    float tm = -1e30f;
#pragma unroll
    for (int r = 0; r < 16; ++r) {
      const int bit = (r & 3) + 8 * (r >> 2);
      s0[r] = ((mw0 >> bit) & 1u) ? s0[r] : -1e9f;
      s1[r] = ((mw1 >> bit) & 1u) ? s1[r] : -1e9f;
      tm = fmaxf(tm, fmaxf(s0[r], s1[r]));
    }
    tm = fmaxf(tm, __shfl_xor(tm, 32));

    if (__any(tm > mrun + 8.f)) {              // deferred rescale (T13)
      const float mold = mrun;
      mrun = fmaxf(mrun, tm);
      const float corr = __expf(mold - mrun);
      lrun *= corr;
#pragma unroll
      for (int r = 0; r < 16; ++r) { xacc0[r] *= corr; xacc1[r] *= corr; }
    }

    float rs = 0.f;
#pragma unroll
    for (int r = 0; r < 16; ++r) {
      s0[r] = __expf(s0[r] - mrun);
      s1[r] = __expf(s1[r] - mrun);
      rs += s0[r] + s1[r];
    }
    rs += __shfl_xor(rs, 32);
    lrun += rs;

    // ---- pack P -> bf16 B-operand (cvt_pk + permlane32_swap) + PV ----
#pragma unroll
    for (int ks = 0; ks < 4; ++ks) {
      const f32x16& ps = (ks < 2) ? s0 : s1;
      const int base = 8 * (ks & 1);
      u32 w0, w1, w2, w3;
      asm("v_cvt_pk_bf16_f32 %0, %1, %2" : "=v"(w0) : "v"(ps[base + 0]), "v"(ps[base + 1]));
      asm("v_cvt_pk_bf16_f32 %0, %1, %2" : "=v"(w1) : "v"(ps[base + 2]), "v"(ps[base + 3]));
      asm("v_cvt_pk_bf16_f32 %0, %1, %2" : "=v"(w2) : "v"(ps[base + 4]), "v"(ps[base + 5]));
      asm("v_cvt_pk_bf16_f32 %0, %1, %2" : "=v"(w3) : "v"(ps[base + 6]), "v"(ps[base + 7]));
      // vdst = low-k word, vsrc = high-k word (exchange vdst.hi32 <-> vsrc.lo32)
      asm("v_permlane32_swap_b32 %0, %1" : "+v"(w0), "+v"(w2));
      asm("v_permlane32_swap_b32 %0, %1" : "+v"(w1), "+v"(w3));
      union { u32 w[4]; bf16x8 v; } pb;
      pb.w[0] = w0; pb.w[1] = w1; pb.w[2] = w2; pb.w[3] = w3;

      const u16* vp = Vb + (size_t)l31 * S_ + k0 + ks * 16 + hi * 8;
      bf16x8 va0 = *(const bf16x8*)vp;
      bf16x8 va1 = *(const bf16x8*)(vp + (size_t)32 * S_);
      xacc0 = MFMA32(va0, pb.v, xacc0);
      xacc1 = MFMA32(va1, pb.v, xacc1);
    }
  }

  // ---- epilogue: O^T[d][q] -> Xo[token][dmodel], ushort4 stores ----
  const float inv_l = 1.0f / lrun;
  u16* xo = Xo + ((size_t)(b * S_) + q) * D_ + h * 64;
#pragma unroll
  for (int dt = 0; dt < 2; ++dt) {
    const f32x16& xa = dt ? xacc1 : xacc0;
#pragma unroll
    for (int g = 0; g < 4; ++g) {
      ushort4 o;
      o.x = f2bf(xa[4 * g + 0] * inv_l);
      o.y = f2bf(xa[4 * g + 1] * inv_l);
      o.z = f2bf(xa[4 * g + 2] * inv_l);
      o.w = f2bf(xa[4 * g + 3] * inv_l);
      *(ushort4*)(xo + dt * 32 + 8 * g + 4 * hi) = o;
    }
  }
}

// ---------------------------------------------------------------------------
extern "C" void kernel_launch(void* const* d_in, const int* in_sizes, int n_in,
                              void* d_out, int out_size, void* d_ws, size_t ws_size,
                              hipStream_t stream) {
  (void)in_sizes; (void)n_in; (void)out_size; (void)ws_size;
  const float* q   = (const float*)d_in[0];
  const float* kin = (const float*)d_in[1];
  const float* val = (const float*)d_in[2];
  const int*   pad = (const int*)d_in[4];
  const float* Wq = (const float*)d_in[5];
  const float* bq = (const float*)d_in[6];
  const float* Wk = (const float*)d_in[7];
  const float* bk = (const float*)d_in[8];
  const float* Wv = (const float*)d_in[9];
  const float* bv = (const float*)d_in[10];
  const float* Wo = (const float*)d_in[11];
  const float* bo = (const float*)d_in[12];
  float* out = (float*)d_out;

  char* ws = (char*)d_ws;
  const size_t SZ = (size_t)M_ * D_ * sizeof(u16);     // 16.78 MB each
  u16* Qhi = (u16*)(ws + 0 * SZ);
  u16* Qlo = (u16*)(ws + 1 * SZ);
  u16* Khi = (u16*)(ws + 2 * SZ);
  u16* Klo = (u16*)(ws + 3 * SZ);
  u16* Vt  = (u16*)(ws + 4 * SZ);                      // [bh][dk][s]
  u16* Xa  = (u16*)(ws + 5 * SZ);
  u32* mb  = (u32*)(ws + 6 * SZ);                      // 256 words

  dim3 gg(D_ / 128, M_ / 128), bb(256);
  gemm_k<3, 0><<<gg, bb, 0, stream>>>(q,   nullptr, Wq, bq, Qhi, (float*)Qlo, 0.125f);
  gemm_k<3, 0><<<gg, bb, 0, stream>>>(kin, nullptr, Wk, bk, Khi, (float*)Klo, 1.0f);
  gemm_k<1, 1><<<gg, bb, 0, stream>>>(val, nullptr, Wv, bv, Vt,  nullptr,     1.0f);
  maskpack_k<<<dim3(1), dim3(256), 0, stream>>>(pad, mb);

  dim3 ga(S_ / 128, H_, 4);
  attn_k<<<ga, bb, 0, stream>>>(Qhi, Qlo, Khi, Klo, Vt, mb, Xa);

  gemm_k<1, 2><<<gg, bb, 0, stream>>>(nullptr, Xa, Wo, bo, nullptr, out, 1.0f);
}

// Round 4
// 444.156 us; speedup vs baseline: 1.3429x; 1.3429x over previous
//
#include <hip/hip_runtime.h>
#include <hip/hip_bf16.h>

typedef unsigned short u16;
typedef unsigned int u32;
typedef __attribute__((ext_vector_type(8))) short bf16x8;
typedef __attribute__((ext_vector_type(4))) float f32x4;
typedef __attribute__((ext_vector_type(16))) float f32x16;

#define DEVI __device__ __forceinline__

constexpr int S_ = 2048, H_ = 16, D_ = 1024, M_ = 8192;

DEVI u16 f2bf(float f) {
  unsigned int u = __float_as_uint(f);
  u += 0x7fffu + ((u >> 16) & 1u);   // RTNE
  return (u16)(u >> 16);
}
DEVI float bf2f(u16 h) { return __uint_as_float(((unsigned int)h) << 16); }

DEVI f32x4 MFMA16(bf16x8 a, bf16x8 b, f32x4 c) {
  return __builtin_amdgcn_mfma_f32_16x16x32_bf16(a, b, c, 0, 0, 0);
}
DEVI f32x16 MFMA32(bf16x8 a, bf16x8 b, f32x16 c) {
  return __builtin_amdgcn_mfma_f32_32x32x16_bf16(a, b, c, 0, 0, 0);
}

// ---------------------------------------------------------------------------
// GEMM: C[m][n] = sum_k A[m][k] * W[n][k] + bias[n]   (A: M x 1024, W: 1024 x 1024)
// TERMS=3: error-compensated hi/lo split. TERMS=1: plain bf16 path.
// EPI=0: write (v*oscale) as bf16 hi+lo scattered to (B,H,S,DK)   (Q/K proj)
// EPI=1: MFMA operands swapped (acc holds C^T); write bf16 V^T [bh][dk][s]
// EPI=2: A is bf16 row-major; write f32 row-major                 (out proj)
// ---------------------------------------------------------------------------
template<int TERMS, int EPI>
__global__ __launch_bounds__(256)
void gemm_k(const float* __restrict__ Af, const u16* __restrict__ Ab,
            const float* __restrict__ W, const float* __restrict__ bias,
            u16* __restrict__ oB, float* __restrict__ oLoF, float oscale)
{
  constexpr int LDT = 40;                      // 80B row stride
  __shared__ u16 Ah[128 * LDT];
  __shared__ u16 Al[(TERMS == 3) ? 128 * LDT : 8];
  __shared__ u16 Wh[128 * LDT];
  __shared__ u16 Wl[(TERMS == 3) ? 128 * LDT : 8];

  const int tid = threadIdx.x;
  const int lane = tid & 63;
  const int wv = tid >> 6;
  const int wr = wv >> 1, wc = wv & 1;
  const int l15 = lane & 15, l16 = lane >> 4;
  const int m0 = blockIdx.y * 128, n0 = blockIdx.x * 128;

  f32x4 acc[4][4];
  for (int i = 0; i < 4; ++i)
    for (int j = 0; j < 4; ++j) acc[i][j] = f32x4{0.f, 0.f, 0.f, 0.f};

  for (int kt = 0; kt < D_; kt += 32) {
    __syncthreads();
    if constexpr (EPI == 2) {
      const int r = tid >> 2, c = (tid & 3) * 8;
      for (int p = 0; p < 2; ++p) {
        const int row = r + p * 64;
        bf16x8 v = *(const bf16x8*)(Ab + (size_t)(m0 + row) * D_ + kt + c);
        *(bf16x8*)&Ah[row * LDT + c] = v;
      }
    } else {
      const int r = tid >> 3, c = (tid & 7) * 4;
      for (int p = 0; p < 4; ++p) {
        const int row = r + p * 32;
        float4 v = *(const float4*)(Af + (size_t)(m0 + row) * D_ + kt + c);
        u16 h0 = f2bf(v.x), h1 = f2bf(v.y), h2 = f2bf(v.z), h3 = f2bf(v.w);
        *(ushort4*)&Ah[row * LDT + c] = make_ushort4(h0, h1, h2, h3);
        if constexpr (TERMS == 3) {
          *(ushort4*)&Al[row * LDT + c] =
              make_ushort4(f2bf(v.x - bf2f(h0)), f2bf(v.y - bf2f(h1)),
                           f2bf(v.z - bf2f(h2)), f2bf(v.w - bf2f(h3)));
        }
      }
    }
    {
      const int r = tid >> 3, c = (tid & 7) * 4;
      for (int p = 0; p < 4; ++p) {
        const int row = r + p * 32;
        float4 v = *(const float4*)(W + (size_t)(n0 + row) * D_ + kt + c);
        u16 h0 = f2bf(v.x), h1 = f2bf(v.y), h2 = f2bf(v.z), h3 = f2bf(v.w);
        *(ushort4*)&Wh[row * LDT + c] = make_ushort4(h0, h1, h2, h3);
        if constexpr (TERMS == 3) {
          *(ushort4*)&Wl[row * LDT + c] =
              make_ushort4(f2bf(v.x - bf2f(h0)), f2bf(v.y - bf2f(h1)),
                           f2bf(v.z - bf2f(h2)), f2bf(v.w - bf2f(h3)));
        }
      }
    }
    __syncthreads();

    bf16x8 a_hi[4], w_hi[4], a_lo[4], w_lo[4];
    for (int i = 0; i < 4; ++i) {
      const int row = wr * 64 + i * 16 + l15;
      a_hi[i] = *(const bf16x8*)&Ah[row * LDT + l16 * 8];
      if constexpr (TERMS == 3) a_lo[i] = *(const bf16x8*)&Al[row * LDT + l16 * 8];
    }
    for (int j = 0; j < 4; ++j) {
      const int row = wc * 64 + j * 16 + l15;
      w_hi[j] = *(const bf16x8*)&Wh[row * LDT + l16 * 8];
      if constexpr (TERMS == 3) w_lo[j] = *(const bf16x8*)&Wl[row * LDT + l16 * 8];
    }
    for (int i = 0; i < 4; ++i)
      for (int j = 0; j < 4; ++j) {
        if constexpr (EPI == 1) {
          acc[i][j] = MFMA16(w_hi[j], a_hi[i], acc[i][j]);   // C^T
        } else {
          acc[i][j] = MFMA16(a_hi[i], w_hi[j], acc[i][j]);
          if constexpr (TERMS == 3) {
            acc[i][j] = MFMA16(a_hi[i], w_lo[j], acc[i][j]);
            acc[i][j] = MFMA16(a_lo[i], w_hi[j], acc[i][j]);
          }
        }
      }
  }

  if constexpr (EPI == 1) {
    // acc[i][j]: rows = n (l16*4+r), cols = m (l15). Write V^T coalesced in s.
    for (int j = 0; j < 4; ++j)
      for (int i = 0; i < 4; ++i)
        for (int r = 0; r < 4; ++r) {
          const int n = n0 + wc * 64 + j * 16 + l16 * 4 + r;
          const int m = m0 + wr * 64 + i * 16 + l15;
          const float v = (acc[i][j][r] + bias[n]) * oscale;
          const int b = m >> 11, s = m & 2047, h = n >> 6, dk = n & 63;
          oB[((size_t)(b * H_ + h) * 64 + dk) * S_ + s] = f2bf(v);
        }
  } else {
    for (int j = 0; j < 4; ++j) {
      const int n = n0 + wc * 64 + j * 16 + l15;
      const float bj = bias[n];
      for (int i = 0; i < 4; ++i)
        for (int r = 0; r < 4; ++r) {
          const int m = m0 + wr * 64 + i * 16 + l16 * 4 + r;
          const float v = (acc[i][j][r] + bj) * oscale;
          if constexpr (EPI == 2) {
            oLoF[(size_t)m * D_ + n] = v;
          } else {
            const int b = m >> 11, s = m & 2047, h = n >> 6, dk = n & 63;
            const size_t idx = ((size_t)(b * H_ + h) * S_ + s) * 64 + dk;
            const u16 hv = f2bf(v);
            oB[idx] = hv;
            ((u16*)oLoF)[idx] = f2bf(v - bf2f(hv));
          }
        }
    }
  }
}

// ---------------------------------------------------------------------------
__global__ void maskpack_k(const int* __restrict__ pad, u32* __restrict__ mb) {
  const int t = threadIdx.x;                   // 256 words cover 4*2048 ints
  u32 w = 0;
  for (int i = 0; i < 32; ++i) w |= (pad[t * 32 + i] ? 1u : 0u) << i;
  mb[t] = w;
}

// ---------------------------------------------------------------------------
// Fused flash attention, m214-style: 8 waves x 32 q-rows = 256 q/block.
// K(hi,lo) and V^T staged to LDS, double-buffered, XOR-swizzled (slot^=(row&7)).
// T14 split: global loads issued at top of compute, ds_write after compute,
// one __syncthreads per 64-key tile (its vmcnt/lgkm drain = 2-phase semantics).
// Swapped QK^T (S^T = K*Q^T), in-lane softmax over 32-key sub-tiles,
// P packed via v_cvt_pk_bf16_f32 + v_permlane32_swap (vdst=low-k, vsrc=high-k).
// XCD-chunked block swizzle: 8 q-blocks of one (b,h) -> same XCD (L2-resident).
// 1/sqrt(64) pre-folded into Q projection. mrun init 0 (shift-invariant).
// ---------------------------------------------------------------------------
__global__ __launch_bounds__(512, 4)
void attn_k(const u16* __restrict__ Qhi, const u16* __restrict__ Qlo,
            const u16* __restrict__ Khi, const u16* __restrict__ Klo,
            const u16* __restrict__ Vt, const u32* __restrict__ mb,
            u16* __restrict__ Xo)
{
  __shared__ u16 KhS[2][64 * 64];
  __shared__ u16 KlS[2][64 * 64];
  __shared__ u16 VtS[2][64 * 64];

  const int tid = threadIdx.x;
  const int lane = tid & 63;
  const int wv = tid >> 6;                     // 0..7
  const int l31 = lane & 31;
  const int hi = lane >> 5;

  // XCD-chunked bijective swizzle: nwg=512, 64 blocks per XCD = 8 (b,h).
  const int bid = blockIdx.x;
  const int nb = (bid & 7) * 64 + (bid >> 3);
  const int qb = nb & 7;                       // q-block fastest within XCD
  const int bh = nb >> 3;                      // 0..63 = b*H + h
  const int b = bh >> 4;
  const int q = qb * 256 + wv * 32 + l31;

  const u16* Qh = Qhi + (size_t)bh * S_ * 64;
  const u16* Ql = Qlo + (size_t)bh * S_ * 64;
  const u16* Kh = Khi + (size_t)bh * S_ * 64;
  const u16* Kl = Klo + (size_t)bh * S_ * 64;
  const u16* Vb = Vt + (size_t)bh * 64 * S_;
  const u32* mbb = mb + b * (S_ / 32);

  // staging geometry: wave wv stages local rows wv*8..wv*8+7 of each matrix
  const int lr = lane >> 3, c8 = lane & 7;
  const int srow = wv * 8 + lr;                // 0..63
  const int sdst = srow * 64 + ((c8 ^ (srow & 7)) * 8);   // swizzled LDS u16 idx
  const u16* gKh = Kh + (size_t)srow * 64 + c8 * 8;       // + k0*64 per tile
  const u16* gKl = Kl + (size_t)srow * 64 + c8 * 8;
  const u16* gVt = Vb + (size_t)srow * S_ + c8 * 8;       // + k0 per tile

  // Q fragments in registers for the whole kernel
  bf16x8 qh[4], ql[4];
#pragma unroll
  for (int ds = 0; ds < 4; ++ds) {
    qh[ds] = *(const bf16x8*)(Qh + (size_t)q * 64 + ds * 16 + hi * 8);
    ql[ds] = *(const bf16x8*)(Ql + (size_t)q * 64 + ds * 16 + hi * 8);
  }

  f32x16 xacc0, xacc1;
#pragma unroll
  for (int r = 0; r < 16; ++r) { xacc0[r] = 0.f; xacc1[r] = 0.f; }
  float mrun = 0.f, lrun = 0.f;

  // prologue: stage tile 0
  {
    bf16x8 rkh = *(const bf16x8*)gKh;
    bf16x8 rkl = *(const bf16x8*)gKl;
    bf16x8 rvt = *(const bf16x8*)gVt;
    *(bf16x8*)&KhS[0][sdst] = rkh;
    *(bf16x8*)&KlS[0][sdst] = rkl;
    *(bf16x8*)&VtS[0][sdst] = rvt;
  }
  __syncthreads();

  const int vx = l31 & 7;

  for (int it = 0; it < 32; ++it) {
    const int cur = it & 1;
    const int k0 = it * 64;

    // ---- A: issue next-tile global loads (latency hidden under compute) ----
    bf16x8 rkh, rkl, rvt;
    const bool have = (it + 1 < 32);
    if (have) {
      const size_t ko = (size_t)(it + 1) * 64;
      rkh = *(const bf16x8*)(gKh + ko * 64);
      rkl = *(const bf16x8*)(gKl + ko * 64);
      rvt = *(const bf16x8*)(gVt + ko);
    }

    // ---- B: compute tile it from buf[cur], two 32-key sub-tiles ----
#pragma unroll
    for (int sub = 0; sub < 2; ++sub) {
      f32x16 s;
#pragma unroll
      for (int r = 0; r < 16; ++r) s[r] = 0.f;
      const int kr = sub * 32 + l31;
      const int krx = kr & 7;
      const u16* KH = &KhS[cur][kr * 64];
      const u16* KL = &KlS[cur][kr * 64];
      __builtin_amdgcn_s_setprio(1);
#pragma unroll
      for (int ds = 0; ds < 4; ++ds) {
        const int sl = ((2 * ds + hi) ^ krx) * 8;
        bf16x8 kh = *(const bf16x8*)(KH + sl);
        bf16x8 kl = *(const bf16x8*)(KL + sl);
        s = MFMA32(kh, qh[ds], s);
        s = MFMA32(kl, qh[ds], s);
        s = MFMA32(kh, ql[ds], s);
      }
      __builtin_amdgcn_s_setprio(0);

      // mask + sub-tile max
      const u32 mw = mbb[(k0 >> 5) + sub] >> (hi * 4);
      float tm = -1e30f;
#pragma unroll
      for (int r = 0; r < 16; ++r) {
        const int bit = (r & 3) + 8 * (r >> 2);
        s[r] = ((mw >> bit) & 1u) ? s[r] : -1e9f;
        tm = fmaxf(tm, s[r]);
      }
      tm = fmaxf(tm, __shfl_xor(tm, 32));

      if (__any(tm > mrun + 8.f)) {            // deferred rescale (T13)
        const float mold = mrun;
        mrun = fmaxf(mrun, tm);
        const float corr = __expf(mold - mrun);
        lrun *= corr;
#pragma unroll
        for (int r = 0; r < 16; ++r) { xacc0[r] *= corr; xacc1[r] *= corr; }
      }

      float rs = 0.f;
#pragma unroll
      for (int r = 0; r < 16; ++r) {
        s[r] = __expf(s[r] - mrun);
        rs += s[r];
      }
      rs += __shfl_xor(rs, 32);
      lrun += rs;

      // pack P -> bf16 B-operand + PV
#pragma unroll
      for (int ks = 0; ks < 2; ++ks) {
        const int base = 8 * ks;
        u32 w0, w1, w2, w3;
        asm("v_cvt_pk_bf16_f32 %0, %1, %2" : "=v"(w0) : "v"(s[base + 0]), "v"(s[base + 1]));
        asm("v_cvt_pk_bf16_f32 %0, %1, %2" : "=v"(w1) : "v"(s[base + 2]), "v"(s[base + 3]));
        asm("v_cvt_pk_bf16_f32 %0, %1, %2" : "=v"(w2) : "v"(s[base + 4]), "v"(s[base + 5]));
        asm("v_cvt_pk_bf16_f32 %0, %1, %2" : "=v"(w3) : "v"(s[base + 6]), "v"(s[base + 7]));
        // vdst = low-k word, vsrc = high-k word
        asm("v_permlane32_swap_b32 %0, %1" : "+v"(w0), "+v"(w2));
        asm("v_permlane32_swap_b32 %0, %1" : "+v"(w1), "+v"(w3));
        union { u32 w[4]; bf16x8 v; } pb;
        pb.w[0] = w0; pb.w[1] = w1; pb.w[2] = w2; pb.w[3] = w3;

        const int slv = ((sub * 4 + ks * 2 + hi) ^ vx) * 8;
        bf16x8 va0 = *(const bf16x8*)&VtS[cur][l31 * 64 + slv];
        bf16x8 va1 = *(const bf16x8*)&VtS[cur][(l31 + 32) * 64 + slv];
        __builtin_amdgcn_s_setprio(1);
        xacc0 = MFMA32(va0, pb.v, xacc0);
        xacc1 = MFMA32(va1, pb.v, xacc1);
        __builtin_amdgcn_s_setprio(0);
      }
    }

    // ---- C: ds_write staged regs into the other buffer ----
    if (have) {
      *(bf16x8*)&KhS[cur ^ 1][sdst] = rkh;
      *(bf16x8*)&KlS[cur ^ 1][sdst] = rkl;
      *(bf16x8*)&VtS[cur ^ 1][sdst] = rvt;
    }
    __syncthreads();
  }

  // ---- epilogue: O^T[d][q] -> Xo[token][dmodel], ushort4 stores ----
  const float inv_l = 1.0f / lrun;
  u16* xo = Xo + ((size_t)(b * S_) + q) * D_ + (bh & 15) * 64;
#pragma unroll
  for (int dt = 0; dt < 2; ++dt) {
    const f32x16& xa = dt ? xacc1 : xacc0;
#pragma unroll
    for (int g = 0; g < 4; ++g) {
      ushort4 o;
      o.x = f2bf(xa[4 * g + 0] * inv_l);
      o.y = f2bf(xa[4 * g + 1] * inv_l);
      o.z = f2bf(xa[4 * g + 2] * inv_l);
      o.w = f2bf(xa[4 * g + 3] * inv_l);
      *(ushort4*)(xo + dt * 32 + 8 * g + 4 * hi) = o;
    }
  }
}

// ---------------------------------------------------------------------------
extern "C" void kernel_launch(void* const* d_in, const int* in_sizes, int n_in,
                              void* d_out, int out_size, void* d_ws, size_t ws_size,
                              hipStream_t stream) {
  (void)in_sizes; (void)n_in; (void)out_size; (void)ws_size;
  const float* q   = (const float*)d_in[0];
  const float* kin = (const float*)d_in[1];
  const float* val = (const float*)d_in[2];
  const int*   pad = (const int*)d_in[4];
  const float* Wq = (const float*)d_in[5];
  const float* bq = (const float*)d_in[6];
  const float* Wk = (const float*)d_in[7];
  const float* bk = (const float*)d_in[8];
  const float* Wv = (const float*)d_in[9];
  const float* bv = (const float*)d_in[10];
  const float* Wo = (const float*)d_in[11];
  const float* bo = (const float*)d_in[12];
  float* out = (float*)d_out;

  char* ws = (char*)d_ws;
  const size_t SZ = (size_t)M_ * D_ * sizeof(u16);     // 16.78 MB each
  u16* Qhi = (u16*)(ws + 0 * SZ);
  u16* Qlo = (u16*)(ws + 1 * SZ);
  u16* Khi = (u16*)(ws + 2 * SZ);
  u16* Klo = (u16*)(ws + 3 * SZ);
  u16* Vt  = (u16*)(ws + 4 * SZ);                      // [bh][dk][s]
  u16* Xa  = (u16*)(ws + 5 * SZ);
  u32* mb  = (u32*)(ws + 6 * SZ);                      // 256 words

  dim3 gg(D_ / 128, M_ / 128), bb(256);
  gemm_k<3, 0><<<gg, bb, 0, stream>>>(q,   nullptr, Wq, bq, Qhi, (float*)Qlo, 0.125f);
  gemm_k<3, 0><<<gg, bb, 0, stream>>>(kin, nullptr, Wk, bk, Khi, (float*)Klo, 1.0f);
  gemm_k<1, 1><<<gg, bb, 0, stream>>>(val, nullptr, Wv, bv, Vt,  nullptr,     1.0f);
  maskpack_k<<<dim3(1), dim3(256), 0, stream>>>(pad, mb);

  attn_k<<<dim3(512), dim3(512), 0, stream>>>(Qhi, Qlo, Khi, Klo, Vt, mb, Xa);

  gemm_k<1, 2><<<gg, bb, 0, stream>>>(nullptr, Xa, Wo, bo, nullptr, out, 1.0f);
}

// Round 5
// 390.267 us; speedup vs baseline: 1.5284x; 1.1381x over previous
//
#include <hip/hip_runtime.h>
#include <hip/hip_bf16.h>

typedef unsigned short u16;
typedef unsigned int u32;
typedef __attribute__((ext_vector_type(8))) short bf16x8;
typedef __attribute__((ext_vector_type(4))) float f32x4;
typedef __attribute__((ext_vector_type(16))) float f32x16;

#define DEVI __device__ __forceinline__

constexpr int S_ = 2048, H_ = 16, D_ = 1024, M_ = 8192;

DEVI u16 f2bf(float f) {
  unsigned int u = __float_as_uint(f);
  u += 0x7fffu + ((u >> 16) & 1u);   // RTNE
  return (u16)(u >> 16);
}
DEVI float bf2f(u16 h) { return __uint_as_float(((unsigned int)h) << 16); }

DEVI f32x4 MFMA16(bf16x8 a, bf16x8 b, f32x4 c) {
  return __builtin_amdgcn_mfma_f32_16x16x32_bf16(a, b, c, 0, 0, 0);
}
DEVI f32x16 MFMA32(bf16x8 a, bf16x8 b, f32x16 c) {
  return __builtin_amdgcn_mfma_f32_32x32x16_bf16(a, b, c, 0, 0, 0);
}

// direct-to-LDS 16B async copy: linear dest (wave-uniform base + lane*16)
#define GLOAD16(gp, lp) __builtin_amdgcn_global_load_lds( \
    (const __attribute__((address_space(1))) void*)(gp),  \
    (__attribute__((address_space(3))) void*)(lp), 16, 0, 0)

// ---------------------------------------------------------------------------
// f32 -> bf16 hi (+ optional lo residual), 8 elements/thread, memory-bound.
// ---------------------------------------------------------------------------
template<bool LO>
__global__ __launch_bounds__(256)
void conv_k(const float* __restrict__ in, u16* __restrict__ hi,
            u16* __restrict__ lo, int n8)
{
  const int i = blockIdx.x * 256 + threadIdx.x;
  if (i >= n8) return;
  const float4* p = (const float4*)in + 2 * (size_t)i;
  const float4 v0 = p[0], v1 = p[1];
  const float f[8] = {v0.x, v0.y, v0.z, v0.w, v1.x, v1.y, v1.z, v1.w};
  u16 h[8], l[8];
#pragma unroll
  for (int j = 0; j < 8; ++j) {
    h[j] = f2bf(f[j]);
    if (LO) l[j] = f2bf(f[j] - bf2f(h[j]));
  }
  *(ushort4*)(hi + 8 * (size_t)i)     = make_ushort4(h[0], h[1], h[2], h[3]);
  *(ushort4*)(hi + 8 * (size_t)i + 4) = make_ushort4(h[4], h[5], h[6], h[7]);
  if (LO) {
    *(ushort4*)(lo + 8 * (size_t)i)     = make_ushort4(l[0], l[1], l[2], l[3]);
    *(ushort4*)(lo + 8 * (size_t)i + 4) = make_ushort4(l[4], l[5], l[6], l[7]);
  }
}

// ---------------------------------------------------------------------------
// GEMM: C[m][n] = sum_k A[m][k]*W[n][k] + bias[n], all inputs pre-split bf16.
// A: M x 1024, W: 1024 x 1024, both row-major bf16 (hi + optional lo).
// m97 structure: global_load_lds(16B) staging, BK=32, 128^2 tile, 2 barriers.
// LDS both-sides swizzle (rule #21): linear dest, source col-slot
// pre-XORed with ((row>>1)&3), ds_read applies the same XOR -> 2-way banks.
// TERMS=3: acc += Ah*Wh + Ah*Wl + Al*Wh  (error-compensated).
// EPI=0: write (v*oscale) bf16 hi+lo scattered to (B,H,S,DK)   (Q/K proj)
// EPI=1: MFMA operands swapped (acc = C^T); write bf16 V^T [bh][dk][s]
// EPI=2: write f32 row-major                                    (out proj)
// Grid: flat 512 blocks, XCD-chunked bijective swizzle (8 XCDs).
// ---------------------------------------------------------------------------
template<int TERMS, int EPI>
__global__ __launch_bounds__(256)
void gemm_k(const u16* __restrict__ Ahg, const u16* __restrict__ Alg,
            const u16* __restrict__ Whg, const u16* __restrict__ Wlg,
            const float* __restrict__ bias,
            u16* __restrict__ oHi, u16* __restrict__ oLo,
            float* __restrict__ oF, float oscale)
{
  __shared__ u16 AhS[128 * 32];
  __shared__ u16 WhS[128 * 32];
  __shared__ u16 AlS[(TERMS == 3) ? 128 * 32 : 8];
  __shared__ u16 WlS[(TERMS == 3) ? 128 * 32 : 8];

  const int tid = threadIdx.x;
  const int lane = tid & 63;
  const int wv = tid >> 6;
  const int wr = wv >> 1, wc = wv & 1;
  const int l15 = lane & 15, l16 = lane >> 4;

  // XCD-chunked bijective swizzle: 512 blocks = 8 bx x 64 by
  const int bid = blockIdx.x;
  const int nb = (bid & 7) * 64 + (bid >> 3);
  const int bx = nb & 7, by = nb >> 3;
  const int m0 = by * 128, n0 = bx * 128;

  // staging source (per-lane constants): 16 rows x 64B per issue
  const int srow = lane >> 2;                              // 0..15
  const int scol = ((lane & 3) ^ ((lane >> 3) & 3)) * 8;   // inverse-swizzled

  f32x4 acc[4][4];
  for (int i = 0; i < 4; ++i)
    for (int j = 0; j < 4; ++j) acc[i][j] = f32x4{0.f, 0.f, 0.f, 0.f};

  for (int kt = 0; kt < D_; kt += 32) {
#pragma unroll
    for (int p = 0; p < 2; ++p) {
      const int row0 = wv * 32 + p * 16;
      const size_t goA = (size_t)(m0 + row0 + srow) * D_ + kt + scol;
      const size_t goW = (size_t)(n0 + row0 + srow) * D_ + kt + scol;
      GLOAD16(Ahg + goA, &AhS[row0 * 32]);
      GLOAD16(Whg + goW, &WhS[row0 * 32]);
      if constexpr (TERMS == 3) {
        GLOAD16(Alg + goA, &AlS[row0 * 32]);
        GLOAD16(Wlg + goW, &WlS[row0 * 32]);
      }
    }
    __syncthreads();                    // drains vmcnt -> LDS tiles ready

    bf16x8 ah[4], wh[4], al[4], wl[4];
#pragma unroll
    for (int i = 0; i < 4; ++i) {
      const int R = wr * 64 + i * 16 + l15;
      const int sa = R * 32 + ((l16 ^ ((R >> 1) & 3)) * 8);
      ah[i] = *(const bf16x8*)&AhS[sa];
      if constexpr (TERMS == 3) al[i] = *(const bf16x8*)&AlS[sa];
    }
#pragma unroll
    for (int j = 0; j < 4; ++j) {
      const int R = wc * 64 + j * 16 + l15;
      const int sa = R * 32 + ((l16 ^ ((R >> 1) & 3)) * 8);
      wh[j] = *(const bf16x8*)&WhS[sa];
      if constexpr (TERMS == 3) wl[j] = *(const bf16x8*)&WlS[sa];
    }
#pragma unroll
    for (int i = 0; i < 4; ++i)
#pragma unroll
      for (int j = 0; j < 4; ++j) {
        if constexpr (EPI == 1) {
          acc[i][j] = MFMA16(wh[j], ah[i], acc[i][j]);   // C^T
        } else {
          acc[i][j] = MFMA16(ah[i], wh[j], acc[i][j]);
          if constexpr (TERMS == 3) {
            acc[i][j] = MFMA16(ah[i], wl[j], acc[i][j]);
            acc[i][j] = MFMA16(al[i], wh[j], acc[i][j]);
          }
        }
      }
    __syncthreads();                    // compute done before next overwrite
  }

  if constexpr (EPI == 1) {
    // acc rows = n (l16*4+r), cols = m (l15). Write V^T coalesced in s.
    for (int j = 0; j < 4; ++j)
      for (int i = 0; i < 4; ++i)
        for (int r = 0; r < 4; ++r) {
          const int n = n0 + wc * 64 + j * 16 + l16 * 4 + r;
          const int m = m0 + wr * 64 + i * 16 + l15;
          const float v = (acc[i][j][r] + bias[n]) * oscale;
          const int b = m >> 11, s = m & 2047, h = n >> 6, dk = n & 63;
          oHi[((size_t)(b * H_ + h) * 64 + dk) * S_ + s] = f2bf(v);
        }
  } else {
    for (int j = 0; j < 4; ++j) {
      const int n = n0 + wc * 64 + j * 16 + l15;
      const float bj = bias[n];
      for (int i = 0; i < 4; ++i)
        for (int r = 0; r < 4; ++r) {
          const int m = m0 + wr * 64 + i * 16 + l16 * 4 + r;
          const float v = (acc[i][j][r] + bj) * oscale;
          if constexpr (EPI == 2) {
            oF[(size_t)m * D_ + n] = v;
          } else {
            const int b = m >> 11, s = m & 2047, h = n >> 6, dk = n & 63;
            const size_t idx = ((size_t)(b * H_ + h) * S_ + s) * 64 + dk;
            const u16 hv = f2bf(v);
            oHi[idx] = hv;
            oLo[idx] = f2bf(v - bf2f(hv));
          }
        }
    }
  }
}

// ---------------------------------------------------------------------------
__global__ void maskpack_k(const int* __restrict__ pad, u32* __restrict__ mb) {
  const int t = threadIdx.x;                   // 256 words cover 4*2048 ints
  u32 w = 0;
  for (int i = 0; i < 32; ++i) w |= (pad[t * 32 + i] ? 1u : 0u) << i;
  mb[t] = w;
}

// ---------------------------------------------------------------------------
// Fused flash attention, m214-style: 8 waves x 32 q-rows = 256 q/block.
// (unchanged from round 4 — verified at 176 us, absmax 1.95e-3)
// ---------------------------------------------------------------------------
__global__ __launch_bounds__(512, 4)
void attn_k(const u16* __restrict__ Qhi, const u16* __restrict__ Qlo,
            const u16* __restrict__ Khi, const u16* __restrict__ Klo,
            const u16* __restrict__ Vt, const u32* __restrict__ mb,
            u16* __restrict__ Xo)
{
  __shared__ u16 KhS[2][64 * 64];
  __shared__ u16 KlS[2][64 * 64];
  __shared__ u16 VtS[2][64 * 64];

  const int tid = threadIdx.x;
  const int lane = tid & 63;
  const int wv = tid >> 6;                     // 0..7
  const int l31 = lane & 31;
  const int hi = lane >> 5;

  // XCD-chunked bijective swizzle: nwg=512, 64 blocks per XCD = 8 (b,h).
  const int bid = blockIdx.x;
  const int nb = (bid & 7) * 64 + (bid >> 3);
  const int qb = nb & 7;                       // q-block fastest within XCD
  const int bh = nb >> 3;                      // 0..63 = b*H + h
  const int b = bh >> 4;
  const int q = qb * 256 + wv * 32 + l31;

  const u16* Qh = Qhi + (size_t)bh * S_ * 64;
  const u16* Ql = Qlo + (size_t)bh * S_ * 64;
  const u16* Kh = Khi + (size_t)bh * S_ * 64;
  const u16* Kl = Klo + (size_t)bh * S_ * 64;
  const u16* Vb = Vt + (size_t)bh * 64 * S_;
  const u32* mbb = mb + b * (S_ / 32);

  // staging geometry: wave wv stages local rows wv*8..wv*8+7 of each matrix
  const int lr = lane >> 3, c8 = lane & 7;
  const int srow = wv * 8 + lr;                // 0..63
  const int sdst = srow * 64 + ((c8 ^ (srow & 7)) * 8);   // swizzled LDS u16 idx
  const u16* gKh = Kh + (size_t)srow * 64 + c8 * 8;       // + k0*64 per tile
  const u16* gKl = Kl + (size_t)srow * 64 + c8 * 8;
  const u16* gVt = Vb + (size_t)srow * S_ + c8 * 8;       // + k0 per tile

  // Q fragments in registers for the whole kernel
  bf16x8 qh[4], ql[4];
#pragma unroll
  for (int ds = 0; ds < 4; ++ds) {
    qh[ds] = *(const bf16x8*)(Qh + (size_t)q * 64 + ds * 16 + hi * 8);
    ql[ds] = *(const bf16x8*)(Ql + (size_t)q * 64 + ds * 16 + hi * 8);
  }

  f32x16 xacc0, xacc1;
#pragma unroll
  for (int r = 0; r < 16; ++r) { xacc0[r] = 0.f; xacc1[r] = 0.f; }
  float mrun = 0.f, lrun = 0.f;

  // prologue: stage tile 0
  {
    bf16x8 rkh = *(const bf16x8*)gKh;
    bf16x8 rkl = *(const bf16x8*)gKl;
    bf16x8 rvt = *(const bf16x8*)gVt;
    *(bf16x8*)&KhS[0][sdst] = rkh;
    *(bf16x8*)&KlS[0][sdst] = rkl;
    *(bf16x8*)&VtS[0][sdst] = rvt;
  }
  __syncthreads();

  const int vx = l31 & 7;

  for (int it = 0; it < 32; ++it) {
    const int cur = it & 1;
    const int k0 = it * 64;

    // ---- A: issue next-tile global loads (latency hidden under compute) ----
    bf16x8 rkh, rkl, rvt;
    const bool have = (it + 1 < 32);
    if (have) {
      const size_t ko = (size_t)(it + 1) * 64;
      rkh = *(const bf16x8*)(gKh + ko * 64);
      rkl = *(const bf16x8*)(gKl + ko * 64);
      rvt = *(const bf16x8*)(gVt + ko);
    }

    // ---- B: compute tile it from buf[cur], two 32-key sub-tiles ----
#pragma unroll
    for (int sub = 0; sub < 2; ++sub) {
      f32x16 s;
#pragma unroll
      for (int r = 0; r < 16; ++r) s[r] = 0.f;
      const int kr = sub * 32 + l31;
      const int krx = kr & 7;
      const u16* KH = &KhS[cur][kr * 64];
      const u16* KL = &KlS[cur][kr * 64];
      __builtin_amdgcn_s_setprio(1);
#pragma unroll
      for (int ds = 0; ds < 4; ++ds) {
        const int sl = ((2 * ds + hi) ^ krx) * 8;
        bf16x8 kh = *(const bf16x8*)(KH + sl);
        bf16x8 kl = *(const bf16x8*)(KL + sl);
        s = MFMA32(kh, qh[ds], s);
        s = MFMA32(kl, qh[ds], s);
        s = MFMA32(kh, ql[ds], s);
      }
      __builtin_amdgcn_s_setprio(0);

      // mask + sub-tile max
      const u32 mw = mbb[(k0 >> 5) + sub] >> (hi * 4);
      float tm = -1e30f;
#pragma unroll
      for (int r = 0; r < 16; ++r) {
        const int bit = (r & 3) + 8 * (r >> 2);
        s[r] = ((mw >> bit) & 1u) ? s[r] : -1e9f;
        tm = fmaxf(tm, s[r]);
      }
      tm = fmaxf(tm, __shfl_xor(tm, 32));

      if (__any(tm > mrun + 8.f)) {            // deferred rescale (T13)
        const float mold = mrun;
        mrun = fmaxf(mrun, tm);
        const float corr = __expf(mold - mrun);
        lrun *= corr;
#pragma unroll
        for (int r = 0; r < 16; ++r) { xacc0[r] *= corr; xacc1[r] *= corr; }
      }

      float rs = 0.f;
#pragma unroll
      for (int r = 0; r < 16; ++r) {
        s[r] = __expf(s[r] - mrun);
        rs += s[r];
      }
      rs += __shfl_xor(rs, 32);
      lrun += rs;

      // pack P -> bf16 B-operand + PV
#pragma unroll
      for (int ks = 0; ks < 2; ++ks) {
        const int base = 8 * ks;
        u32 w0, w1, w2, w3;
        asm("v_cvt_pk_bf16_f32 %0, %1, %2" : "=v"(w0) : "v"(s[base + 0]), "v"(s[base + 1]));
        asm("v_cvt_pk_bf16_f32 %0, %1, %2" : "=v"(w1) : "v"(s[base + 2]), "v"(s[base + 3]));
        asm("v_cvt_pk_bf16_f32 %0, %1, %2" : "=v"(w2) : "v"(s[base + 4]), "v"(s[base + 5]));
        asm("v_cvt_pk_bf16_f32 %0, %1, %2" : "=v"(w3) : "v"(s[base + 6]), "v"(s[base + 7]));
        // vdst = low-k word, vsrc = high-k word
        asm("v_permlane32_swap_b32 %0, %1" : "+v"(w0), "+v"(w2));
        asm("v_permlane32_swap_b32 %0, %1" : "+v"(w1), "+v"(w3));
        union { u32 w[4]; bf16x8 v; } pb;
        pb.w[0] = w0; pb.w[1] = w1; pb.w[2] = w2; pb.w[3] = w3;

        const int slv = ((sub * 4 + ks * 2 + hi) ^ vx) * 8;
        bf16x8 va0 = *(const bf16x8*)&VtS[cur][l31 * 64 + slv];
        bf16x8 va1 = *(const bf16x8*)&VtS[cur][(l31 + 32) * 64 + slv];
        __builtin_amdgcn_s_setprio(1);
        xacc0 = MFMA32(va0, pb.v, xacc0);
        xacc1 = MFMA32(va1, pb.v, xacc1);
        __builtin_amdgcn_s_setprio(0);
      }
    }

    // ---- C: ds_write staged regs into the other buffer ----
    if (have) {
      *(bf16x8*)&KhS[cur ^ 1][sdst] = rkh;
      *(bf16x8*)&KlS[cur ^ 1][sdst] = rkl;
      *(bf16x8*)&VtS[cur ^ 1][sdst] = rvt;
    }
    __syncthreads();
  }

  // ---- epilogue: O^T[d][q] -> Xo[token][dmodel], ushort4 stores ----
  const float inv_l = 1.0f / lrun;
  u16* xo = Xo + ((size_t)(b * S_) + q) * D_ + (bh & 15) * 64;
#pragma unroll
  for (int dt = 0; dt < 2; ++dt) {
    const f32x16& xa = dt ? xacc1 : xacc0;
#pragma unroll
    for (int g = 0; g < 4; ++g) {
      ushort4 o;
      o.x = f2bf(xa[4 * g + 0] * inv_l);
      o.y = f2bf(xa[4 * g + 1] * inv_l);
      o.z = f2bf(xa[4 * g + 2] * inv_l);
      o.w = f2bf(xa[4 * g + 3] * inv_l);
      *(ushort4*)(xo + dt * 32 + 8 * g + 4 * hi) = o;
    }
  }
}

// ---------------------------------------------------------------------------
extern "C" void kernel_launch(void* const* d_in, const int* in_sizes, int n_in,
                              void* d_out, int out_size, void* d_ws, size_t ws_size,
                              hipStream_t stream) {
  (void)in_sizes; (void)n_in; (void)out_size; (void)ws_size;
  const float* q   = (const float*)d_in[0];
  const float* kin = (const float*)d_in[1];
  const float* val = (const float*)d_in[2];
  const int*   pad = (const int*)d_in[4];
  const float* Wq = (const float*)d_in[5];
  const float* bq = (const float*)d_in[6];
  const float* Wk = (const float*)d_in[7];
  const float* bk = (const float*)d_in[8];
  const float* Wv = (const float*)d_in[9];
  const float* bv = (const float*)d_in[10];
  const float* Wo = (const float*)d_in[11];
  const float* bo = (const float*)d_in[12];
  float* out = (float*)d_out;

  char* ws = (char*)d_ws;
  const size_t SZ = (size_t)M_ * D_ * sizeof(u16);     // 16.78 MB
  const size_t WSZ = (size_t)D_ * D_ * sizeof(u16);    // 2.10 MB
  u16* Qhi = (u16*)(ws + 0 * SZ);
  u16* Qlo = (u16*)(ws + 1 * SZ);
  u16* Khi = (u16*)(ws + 2 * SZ);
  u16* Klo = (u16*)(ws + 3 * SZ);
  u16* Vt  = (u16*)(ws + 4 * SZ);                      // [bh][dk][s]; aliased C2
  u16* Xa  = (u16*)(ws + 5 * SZ);                      // aliased C1
  u16* WH  = (u16*)(ws + 6 * SZ);
  u16* WL  = (u16*)(ws + 6 * SZ + WSZ);
  u32* mb  = (u32*)(ws + 6 * SZ + 2 * WSZ);            // 256 words
  u16* C1 = Xa;                                         // activation hi (dead before attn writes Xa)
  u16* C2 = Vt;                                         // activation lo (dead before gemm V writes Vt)

  dim3 bb(256);
  const int actN8 = M_ * D_ / 8;                        // 1,048,576
  const int wN8 = D_ * D_ / 8;                          // 131,072
  dim3 ga(actN8 / 256), gw(wN8 / 256), gg(512);

  // Q projection (3-term, scaled by 1/sqrt(64))
  conv_k<true><<<ga, bb, 0, stream>>>(q, C1, C2, actN8);
  conv_k<true><<<gw, bb, 0, stream>>>(Wq, WH, WL, wN8);
  gemm_k<3, 0><<<gg, bb, 0, stream>>>(C1, C2, WH, WL, bq, Qhi, Qlo, nullptr, 0.125f);

  // K projection (3-term)
  conv_k<true><<<ga, bb, 0, stream>>>(kin, C1, C2, actN8);
  conv_k<true><<<gw, bb, 0, stream>>>(Wk, WH, WL, wN8);
  gemm_k<3, 0><<<gg, bb, 0, stream>>>(C1, C2, WH, WL, bk, Khi, Klo, nullptr, 1.0f);

  // V projection (1-term, transposed output)
  conv_k<false><<<ga, bb, 0, stream>>>(val, C1, nullptr, actN8);
  conv_k<false><<<gw, bb, 0, stream>>>(Wv, WH, nullptr, wN8);
  gemm_k<1, 1><<<gg, bb, 0, stream>>>(C1, nullptr, WH, nullptr, bv, Vt, nullptr, nullptr, 1.0f);

  maskpack_k<<<dim3(1), bb, 0, stream>>>(pad, mb);

  attn_k<<<dim3(512), dim3(512), 0, stream>>>(Qhi, Qlo, Khi, Klo, Vt, mb, Xa);

  // output projection (1-term, f32 out)
  conv_k<false><<<gw, bb, 0, stream>>>(Wo, WH, nullptr, wN8);
  gemm_k<1, 2><<<gg, bb, 0, stream>>>(Xa, nullptr, WH, nullptr, bo, nullptr, nullptr, out, 1.0f);
}